// Round 2
// baseline (611.151 us; speedup 1.0000x reference)
//
#include <hip/hip_runtime.h>

// SpectralGNNEncoder on MI355X.
// Math collapse: out = (mu, logvar) where
//   h1 = relu(Agg1(x@W1) + b1)            (Agg1 = sym-norm scatter-add w/ self loops)
//   g  = mean(Agg2(h1@W2)) + b2 = ((1/N) c^T h1) @ W2 + b2,  c[i]=dinv[i]^2+sum_{src=i} norm
//   mu = g@W_mu+b_mu, logvar = g@W_lv+b_lv
// => never materialize h1 or layer-2 aggregation; fuse c^T h1 into layer-1 epilogue.
//
// Dtype-polymorphic: k_detect sniffs whether float tensors are f32 or bf16
// (low ushort of each dword of x: bf16 data decodes sane ~100%, f32 mantissa
// noise ~16%) and every float-tensor load / the output store branches on it.

typedef __bf16 bf16x8 __attribute__((ext_vector_type(8)));
typedef float f32x4 __attribute__((ext_vector_type(4)));

__device__ __forceinline__ float bf2f(unsigned short u){
  return __uint_as_float(((unsigned)u) << 16);
}
__device__ __forceinline__ unsigned short f2bf(float f){
  unsigned u = __float_as_uint(f);
  u += 0x7fffu + ((u >> 16) & 1u);   // RNE
  return (unsigned short)(u >> 16);
}
__device__ __forceinline__ __bf16 us2bf(unsigned short u){
  __bf16 b; __builtin_memcpy(&b, &u, 2); return b;
}
// load element i of a float tensor that is either f32 or bf16
__device__ __forceinline__ float ldf(const void* p, int i, int isf32){
  return isf32 ? ((const float*)p)[i] : bf2f(((const unsigned short*)p)[i]);
}

// ---------- dtype sniffer: flag=1 iff x is float32 ----------
__global__ void k_detect(const unsigned* __restrict__ xw, int* __restrict__ flag){
  __shared__ int s[256];
  int t = threadIdx.x;
  int cnt = 0;
  for (int i = t; i < 4096; i += 256){
    unsigned lo = xw[i] & 0xFFFFu;           // bf16 case: this IS element 2i
    int e = (int)((lo >> 7) & 0xFFu);        // bf16 exponent field
    if ((e >= 100 && e <= 141) || (lo & 0x7FFFu) == 0) cnt++;
  }
  s[t] = cnt;
  __syncthreads();
  for (int off = 128; off > 0; off >>= 1){
    if (t < off) s[t] += s[t + off];
    __syncthreads();
  }
  if (t == 0) *flag = (s[0] < 2458) ? 1 : 0; // <60% sane -> f32
}

// ---------- init: deg=1 (self loop weight), cnt=0, v=0 ----------
__global__ void k_init(float* __restrict__ deg, int* __restrict__ cnt,
                       float* __restrict__ v, int N){
  int i = blockIdx.x * 256 + threadIdx.x;
  if (i < N){ deg[i] = 1.0f; cnt[i] = 0; }
  if (i < 128) v[i] = 0.0f;
}

// ---------- per-edge: weighted in-degree + dst histogram ----------
__global__ void k_deg_hist(const int* __restrict__ dst, const void* __restrict__ w,
                           float* __restrict__ deg, int* __restrict__ cnt, int E,
                           const int* __restrict__ flagp){
  int e = blockIdx.x * 256 + threadIdx.x;
  if (e >= E) return;
  int isf32 = *flagp;
  int d = dst[e];
  atomicAdd(&deg[d], ldf(w, e, isf32));
  atomicAdd(&cnt[d], 1);
}

// ---------- dinv = rsqrt(deg) in place; c init = dinv^2 ----------
__global__ void k_dinv(float* __restrict__ deg_dinv, float* __restrict__ cfac, int N){
  int i = blockIdx.x * 256 + threadIdx.x;
  if (i >= N) return;
  float di = rsqrtf(deg_dinv[i]);
  deg_dinv[i] = di;
  cfac[i] = di * di;
}

// ---------- exclusive scan of cnt -> rowptr (3 kernels) ----------
__global__ void k_scanA(const int* __restrict__ cnt, int* __restrict__ rowptr,
                        int* __restrict__ bsum, int N){
  __shared__ int s[256];
  int i = blockIdx.x * 256 + threadIdx.x;
  int val = (i < N) ? cnt[i] : 0;
  s[threadIdx.x] = val;
  __syncthreads();
  for (int off = 1; off < 256; off <<= 1){
    int tmp = (threadIdx.x >= off) ? s[threadIdx.x - off] : 0;
    __syncthreads();
    s[threadIdx.x] += tmp;
    __syncthreads();
  }
  if (i < N) rowptr[i] = s[threadIdx.x] - val;
  if (threadIdx.x == 255) bsum[blockIdx.x] = s[255];
}

__global__ void k_scanB(const int* __restrict__ bsum, int* __restrict__ boffs, int NB){
  __shared__ int s[512];
  int t = threadIdx.x;
  int val = (t < NB) ? bsum[t] : 0;
  s[t] = val;
  __syncthreads();
  for (int off = 1; off < 512; off <<= 1){
    int tmp = (t >= off) ? s[t - off] : 0;
    __syncthreads();
    s[t] += tmp;
    __syncthreads();
  }
  boffs[t] = s[t] - val;
}

__global__ void k_scanC(int* __restrict__ rowptr, const int* __restrict__ boffs,
                        int* __restrict__ cursor, int N){
  int i = blockIdx.x * 256 + threadIdx.x;
  if (i >= N) return;
  int rp = rowptr[i] + boffs[blockIdx.x];
  rowptr[i] = rp;
  cursor[i] = rp;
}

// ---------- fill CSR (packed src+norm), accumulate c[src] ----------
__global__ void k_fill(const int* __restrict__ src, const int* __restrict__ dst,
                       const void* __restrict__ w, const float* __restrict__ dinv,
                       int* __restrict__ cursor, int2* __restrict__ edges,
                       float* __restrict__ cfac, int E, const int* __restrict__ flagp){
  int e = blockIdx.x * 256 + threadIdx.x;
  if (e >= E) return;
  int isf32 = *flagp;
  int s_ = src[e], d_ = dst[e];
  float nrm = dinv[s_] * ldf(w, e, isf32) * dinv[d_];
  int pos = atomicAdd(&cursor[d_], 1);
  edges[pos] = make_int2(s_, __float_as_int(nrm));
  atomicAdd(&cfac[s_], nrm);
}

// ---------- W1T[n*128+k] = W1[k*128+n], canonical bf16 ----------
__global__ void k_transpose(const void* __restrict__ W1, unsigned short* __restrict__ W1T,
                            const int* __restrict__ flagp){
  int gid = blockIdx.x * 256 + threadIdx.x;   // gid = n*128 + k
  int isf32 = *flagp;
  int k = gid & 127, n = gid >> 7;
  W1T[gid] = isf32 ? f2bf(((const float*)W1)[k * 128 + n])
                   : ((const unsigned short*)W1)[k * 128 + n];
}

// ---------- H = x @ W1, bf16 MFMA 16x16x32, one wave = 16 rows x 128 cols ----------
__global__ void __launch_bounds__(256) k_gemm(const void* __restrict__ xv,
                                              const __bf16* __restrict__ wt,
                                              unsigned short* __restrict__ H, int N,
                                              const int* __restrict__ flagp){
  int wave = (blockIdx.x * blockDim.x + threadIdx.x) >> 6;
  int lane = threadIdx.x & 63;
  int row16 = wave << 4;
  if (row16 >= N) return;                 // N % 16 == 0 (100000)
  int isf32 = *flagp;
  int m = lane & 15, q = lane >> 4;
  // A frag: A[m=lane&15][k=q*8+j]
  bf16x8 a0, a1, a2, a3;
  if (isf32){
    const float* ap = (const float*)xv + (size_t)(row16 + m) * 128 + q * 8;
    #pragma unroll
    for (int j = 0; j < 8; ++j){
      a0[j] = us2bf(f2bf(ap[j +  0]));
      a1[j] = us2bf(f2bf(ap[j + 32]));
      a2[j] = us2bf(f2bf(ap[j + 64]));
      a3[j] = us2bf(f2bf(ap[j + 96]));
    }
  } else {
    const __bf16* ap = (const __bf16*)xv + (size_t)(row16 + m) * 128 + q * 8;
    a0 = *(const bf16x8*)(ap +  0);
    a1 = *(const bf16x8*)(ap + 32);
    a2 = *(const bf16x8*)(ap + 64);
    a3 = *(const bf16x8*)(ap + 96);
  }
  for (int nt = 0; nt < 8; ++nt){
    // B frag: B[k=q*8+j][n=lane&15] -> contiguous in W1T[n][k]
    const __bf16* bp = wt + (size_t)(nt * 16 + m) * 128 + q * 8;
    bf16x8 b0 = *(const bf16x8*)(bp +  0);
    bf16x8 b1 = *(const bf16x8*)(bp + 32);
    bf16x8 b2 = *(const bf16x8*)(bp + 64);
    bf16x8 b3 = *(const bf16x8*)(bp + 96);
    f32x4 acc = {0.f, 0.f, 0.f, 0.f};
    acc = __builtin_amdgcn_mfma_f32_16x16x32_bf16(a0, b0, acc, 0, 0, 0);
    acc = __builtin_amdgcn_mfma_f32_16x16x32_bf16(a1, b1, acc, 0, 0, 0);
    acc = __builtin_amdgcn_mfma_f32_16x16x32_bf16(a2, b2, acc, 0, 0, 0);
    acc = __builtin_amdgcn_mfma_f32_16x16x32_bf16(a3, b3, acc, 0, 0, 0);
    // C/D: col=lane&15, row=q*4+r
    unsigned short* op = H + (size_t)(row16 + q * 4) * 128 + nt * 16 + m;
    op[0]   = f2bf(acc[0]);
    op[128] = f2bf(acc[1]);
    op[256] = f2bf(acc[2]);
    op[384] = f2bf(acc[3]);
  }
}

// ---------- layer-1 aggregation + relu + c-weighted reduction into v[128] ----------
__global__ void __launch_bounds__(256) k_agg(const unsigned short* __restrict__ H,
    const int* __restrict__ rowptr, const int* __restrict__ cnt, const int2* __restrict__ edges,
    const float* __restrict__ dinv, const float* __restrict__ cfac,
    const void* __restrict__ b1, float* __restrict__ v, int N, int totw,
    const int* __restrict__ flagp){
  __shared__ float vsh[128];
  int tid = threadIdx.x;
  if (tid < 128) vsh[tid] = 0.0f;
  __syncthreads();
  int isf32 = *flagp;
  int lane = tid & 63;
  int f = lane * 2;                         // this lane owns features f, f+1
  int gwave = (blockIdx.x * blockDim.x + tid) >> 6;
  float bx = ldf(b1, f, isf32), by = ldf(b1, f + 1, isf32);
  float ax = 0.f, ay = 0.f;
  for (int d = gwave; d < N; d += totw){
    int start = rowptr[d];
    int num   = cnt[d];
    float di  = dinv[d];
    unsigned hv = *(const unsigned*)(H + (size_t)d * 128 + f);
    float w2 = di * di;                     // self-loop norm
    float rx = w2 * __uint_as_float(hv << 16);
    float ry = w2 * __uint_as_float(hv & 0xffff0000u);
    int p = start, pe = start + num;
    for (; p + 4 <= pe; p += 4){            // 4-wide batch: independent loads in flight
      int2 e0 = edges[p + 0], e1 = edges[p + 1], e2 = edges[p + 2], e3 = edges[p + 3];
      unsigned h0 = *(const unsigned*)(H + (size_t)e0.x * 128 + f);
      unsigned h1 = *(const unsigned*)(H + (size_t)e1.x * 128 + f);
      unsigned h2 = *(const unsigned*)(H + (size_t)e2.x * 128 + f);
      unsigned h3 = *(const unsigned*)(H + (size_t)e3.x * 128 + f);
      float n0 = __int_as_float(e0.y), n1 = __int_as_float(e1.y);
      float n2 = __int_as_float(e2.y), n3 = __int_as_float(e3.y);
      rx = fmaf(n0, __uint_as_float(h0 << 16), rx); ry = fmaf(n0, __uint_as_float(h0 & 0xffff0000u), ry);
      rx = fmaf(n1, __uint_as_float(h1 << 16), rx); ry = fmaf(n1, __uint_as_float(h1 & 0xffff0000u), ry);
      rx = fmaf(n2, __uint_as_float(h2 << 16), rx); ry = fmaf(n2, __uint_as_float(h2 & 0xffff0000u), ry);
      rx = fmaf(n3, __uint_as_float(h3 << 16), rx); ry = fmaf(n3, __uint_as_float(h3 & 0xffff0000u), ry);
    }
    for (; p < pe; ++p){
      int2 e = edges[p];
      unsigned h0 = *(const unsigned*)(H + (size_t)e.x * 128 + f);
      float n0 = __int_as_float(e.y);
      rx = fmaf(n0, __uint_as_float(h0 << 16), rx);
      ry = fmaf(n0, __uint_as_float(h0 & 0xffff0000u), ry);
    }
    rx = fmaxf(rx + bx, 0.0f);
    ry = fmaxf(ry + by, 0.0f);
    float cd = cfac[d];
    ax = fmaf(cd, rx, ax);
    ay = fmaf(cd, ry, ay);
  }
  atomicAdd(&vsh[f], ax);
  atomicAdd(&vsh[f + 1], ay);
  __syncthreads();
  if (tid < 128) atomicAdd(&v[tid], vsh[tid]);
}

// ---------- tiny head: g=(v/N)@W2+b2; mu=g@Wmu+bmu; lv=g@Wlv+blv ----------
__global__ void __launch_bounds__(128) k_head(const float* __restrict__ v,
    const void* __restrict__ W2, const void* __restrict__ b2,
    const void* __restrict__ Wmu, const void* __restrict__ bmu,
    const void* __restrict__ Wlv, const void* __restrict__ blv,
    void* __restrict__ outv, float invN, const int* __restrict__ flagp){
  __shared__ float gsh[128];
  __shared__ float tsh[128];
  int t = threadIdx.x;
  int isf32 = *flagp;
  gsh[t] = v[t] * invN;
  __syncthreads();
  float acc = ldf(b2, t, isf32);
  for (int k = 0; k < 128; ++k) acc = fmaf(gsh[k], ldf(W2, k * 128 + t, isf32), acc);
  tsh[t] = acc;
  __syncthreads();
  int j = t & 63;
  const void* Wp = (t < 64) ? Wmu : Wlv;
  float o = ldf((t < 64) ? bmu : blv, j, isf32);
  for (int k = 0; k < 128; ++k) o = fmaf(tsh[k], ldf(Wp, k * 64 + j, isf32), o);
  if (isf32) ((float*)outv)[t] = o;
  else       ((unsigned short*)outv)[t] = f2bf(o);
}

extern "C" void kernel_launch(void* const* d_in, const int* in_sizes, int n_in,
                              void* d_out, int out_size, void* d_ws, size_t ws_size,
                              hipStream_t stream) {
  const void* x   = d_in[0];
  const int*  ei  = (const int*)d_in[1];
  const void* w   = d_in[2];
  const void* W1  = d_in[3];
  const void* b1  = d_in[4];
  const void* W2  = d_in[5];
  const void* b2  = d_in[6];
  const void* Wmu = d_in[7];
  const void* bmu = d_in[8];
  const void* Wlv = d_in[9];
  const void* blv = d_in[10];

  const int N = in_sizes[0] / 128;     // 100000
  const int E = in_sizes[2];           // 1600000
  const int* src = ei;
  const int* dst = ei + E;

  char* wsb = (char*)d_ws;
  size_t off = 0;
  auto alloc = [&](size_t bytes) -> void* {
    off = (off + 15) & ~(size_t)15;
    void* p = wsb + off;
    off += bytes;
    return p;
  };
  int*   flag     = (int*)  alloc(16);
  float* deg_dinv = (float*)alloc((size_t)N * 4);        // deg -> dinv in place
  int*   cnt      = (int*)  alloc((size_t)N * 4);
  int*   rowptr   = (int*)  alloc((size_t)(N + 1) * 4);
  int*   cursor   = (int*)  alloc((size_t)N * 4);
  float* cfac     = (float*)alloc((size_t)N * 4);
  int*   bsum     = (int*)  alloc(512 * 4);
  int*   boffs    = (int*)  alloc(512 * 4);
  float* v        = (float*)alloc(128 * 4);
  unsigned short* W1T = (unsigned short*)alloc(128 * 128 * 2);
  int2*  edges    = (int2*) alloc((size_t)E * 8);
  unsigned short* H = (unsigned short*)alloc((size_t)N * 128 * 2);
  (void)ws_size; (void)n_in; (void)out_size;

  const int nb_n = (N + 255) / 256;    // 391
  const int nb_e = (E + 255) / 256;    // 6250

  k_detect<<<1, 256, 0, stream>>>((const unsigned*)x, flag);
  k_init<<<nb_n, 256, 0, stream>>>(deg_dinv, cnt, v, N);
  k_deg_hist<<<nb_e, 256, 0, stream>>>(dst, w, deg_dinv, cnt, E, flag);
  k_dinv<<<nb_n, 256, 0, stream>>>(deg_dinv, cfac, N);
  k_scanA<<<nb_n, 256, 0, stream>>>(cnt, rowptr, bsum, N);
  k_scanB<<<1, 512, 0, stream>>>(bsum, boffs, nb_n);
  k_scanC<<<nb_n, 256, 0, stream>>>(rowptr, boffs, cursor, N);
  k_fill<<<nb_e, 256, 0, stream>>>(src, dst, w, deg_dinv, cursor, edges, cfac, E, flag);
  k_transpose<<<64, 256, 0, stream>>>(W1, W1T, flag);
  const int nwaves = (N + 15) / 16;
  const int nb_g = (nwaves + 3) / 4;
  k_gemm<<<nb_g, 256, 0, stream>>>(x, (const __bf16*)W1T, H, N, flag);
  const int nb_agg = 2048;
  k_agg<<<nb_agg, 256, 0, stream>>>(H, rowptr, cnt, edges, deg_dinv, cfac, b1, v, N,
                                    nb_agg * 256 / 64, flag);
  k_head<<<1, 128, 0, stream>>>(v, W2, b2, Wmu, bmu, Wlv, blv,
                                d_out, 1.0f / (float)N, flag);
}

// Round 3
// 491.441 us; speedup vs baseline: 1.2436x; 1.2436x over previous
//
#include <hip/hip_runtime.h>

// SpectralGNNEncoder on MI355X.
// out = (mu, logvar):
//   h1 = relu(Agg1(x@W1) + b1)   (sym-norm scatter-add w/ self loops)
//   g  = mean(Agg2(h1@W2)) + b2 = ((1/N) c^T h1) @ W2 + b2,  c[i]=dinv[i]^2+sum_{src=i} norm
// Round 3: u64-packed deg|cnt atomic (rank from returned old), 8 XCD-shadowed
// accumulators, atomic-free CSR fill, quarter-wave gather k_agg.

typedef __bf16 bf16x8 __attribute__((ext_vector_type(8)));
typedef float f32x4 __attribute__((ext_vector_type(4)));
typedef unsigned long long u64;

__device__ __forceinline__ float bf2f(unsigned short u){
  return __uint_as_float(((unsigned)u) << 16);
}
__device__ __forceinline__ unsigned short f2bf(float f){
  unsigned u = __float_as_uint(f);
  u += 0x7fffu + ((u >> 16) & 1u);   // RNE
  return (unsigned short)(u >> 16);
}
__device__ __forceinline__ __bf16 us2bf(unsigned short u){
  __bf16 b; __builtin_memcpy(&b, &u, 2); return b;
}
__device__ __forceinline__ float ldf(const void* p, int i, int isf32){
  return isf32 ? ((const float*)p)[i] : bf2f(((const unsigned short*)p)[i]);
}
// fma 8 bf16 feats (packed in uint4) into acc[8]
__device__ __forceinline__ void fma8(float* acc, float n, uint4 h){
  acc[0] = fmaf(n, __uint_as_float(h.x << 16),        acc[0]);
  acc[1] = fmaf(n, __uint_as_float(h.x & 0xffff0000u), acc[1]);
  acc[2] = fmaf(n, __uint_as_float(h.y << 16),        acc[2]);
  acc[3] = fmaf(n, __uint_as_float(h.y & 0xffff0000u), acc[3]);
  acc[4] = fmaf(n, __uint_as_float(h.z << 16),        acc[4]);
  acc[5] = fmaf(n, __uint_as_float(h.z & 0xffff0000u), acc[5]);
  acc[6] = fmaf(n, __uint_as_float(h.w << 16),        acc[6]);
  acc[7] = fmaf(n, __uint_as_float(h.w & 0xffff0000u), acc[7]);
}

// ---------- dtype sniffer: flag=1 iff float tensors are f32 ----------
__global__ void k_detect(const unsigned* __restrict__ xw, int* __restrict__ flag){
  __shared__ int s[256];
  int t = threadIdx.x;
  int cnt = 0;
  for (int i = t; i < 4096; i += 256){
    unsigned lo = xw[i] & 0xFFFFu;
    int e = (int)((lo >> 7) & 0xFFu);
    if ((e >= 100 && e <= 141) || (lo & 0x7FFFu) == 0) cnt++;
  }
  s[t] = cnt;
  __syncthreads();
  for (int off = 128; off > 0; off >>= 1){
    if (t < off) s[t] += s[t + off];
    __syncthreads();
  }
  if (t == 0) *flag = (s[0] < 2458) ? 1 : 0;
}

// ---------- init: zero shadowed accumulators + v ----------
__global__ void k_init(u64* __restrict__ dc8, float* __restrict__ cfac8,
                       float* __restrict__ v, int N){
  int i = blockIdx.x * 256 + threadIdx.x;
  if (i < N){
    #pragma unroll
    for (int b = 0; b < 8; ++b){
      dc8[(size_t)b * N + i] = 0ull;
      cfac8[(size_t)b * N + i] = 0.0f;
    }
  }
  if (i < 128) v[i] = 0.0f;
}

// ---------- pass1: one u64 atomic = deg(fixed-point) + cnt; old>>40 = rank ----------
__global__ void k_pass1(const int* __restrict__ dst, const void* __restrict__ w,
                        u64* __restrict__ dc8, unsigned* __restrict__ rank,
                        int E, int N, const int* __restrict__ flagp){
  int e = blockIdx.x * 256 + threadIdx.x;
  if (e >= E) return;
  int isf32 = *flagp;
  int d = dst[e];
  float wv = ldf(w, e, isf32);
  u64 wfix = (u64)(wv * 65536.0f + 0.5f);          // 2^-16 fixed point
  int b = blockIdx.x & 7;                          // shadow = XCD-ish
  u64 old = atomicAdd(&dc8[(size_t)b * N + d], (1ull << 40) | wfix);
  rank[e] = (unsigned)(old >> 40);
}

// ---------- merge shadows: dinv, cnt, packed per-shadow prefix bytes ----------
__global__ void k_dinv(const u64* __restrict__ dc8, float* __restrict__ dinv,
                       int* __restrict__ cnt, u64* __restrict__ sbasePk, int N){
  int i = blockIdx.x * 256 + threadIdx.x;
  if (i >= N) return;
  unsigned sb = 0;
  u64 degfix = 0, pk = 0;
  #pragma unroll
  for (int b = 0; b < 8; ++b){
    u64 dcb = dc8[(size_t)b * N + i];
    pk |= ((u64)(sb & 0xFFu)) << (8 * b);          // exclusive prefix for shadow b
    sb += (unsigned)(dcb >> 40);
    degfix += dcb & 0xFFFFFFFFFFull;
  }
  float deg = 1.0f + (float)degfix * (1.0f / 65536.0f);  // +1 self loop
  dinv[i] = rsqrtf(deg);
  cnt[i] = (int)sb;
  sbasePk[i] = pk;
}

// ---------- exclusive scan of cnt -> rowptr ----------
__global__ void k_scanA(const int* __restrict__ cnt, int* __restrict__ rowptr,
                        int* __restrict__ bsum, int N){
  __shared__ int s[256];
  int i = blockIdx.x * 256 + threadIdx.x;
  int val = (i < N) ? cnt[i] : 0;
  s[threadIdx.x] = val;
  __syncthreads();
  for (int off = 1; off < 256; off <<= 1){
    int tmp = (threadIdx.x >= off) ? s[threadIdx.x - off] : 0;
    __syncthreads();
    s[threadIdx.x] += tmp;
    __syncthreads();
  }
  if (i < N) rowptr[i] = s[threadIdx.x] - val;
  if (threadIdx.x == 255) bsum[blockIdx.x] = s[255];
}

__global__ void k_scanB(const int* __restrict__ bsum, int* __restrict__ boffs, int NB){
  __shared__ int s[512];
  int t = threadIdx.x;
  int val = (t < NB) ? bsum[t] : 0;
  s[t] = val;
  __syncthreads();
  for (int off = 1; off < 512; off <<= 1){
    int tmp = (t >= off) ? s[t - off] : 0;
    __syncthreads();
    s[t] += tmp;
    __syncthreads();
  }
  boffs[t] = s[t] - val;
}

__global__ void k_scanC(int* __restrict__ rowptr, const int* __restrict__ boffs, int N){
  int i = blockIdx.x * 256 + threadIdx.x;
  if (i >= N) return;
  rowptr[i] += boffs[blockIdx.x];
}

// ---------- fill CSR: zero returning atomics; shadowed cfac accumulation ----------
__global__ void k_fill(const int* __restrict__ src, const int* __restrict__ dst,
                       const void* __restrict__ w, const float* __restrict__ dinv,
                       const int* __restrict__ rowptr, const u64* __restrict__ sbasePk,
                       const unsigned* __restrict__ rank, int2* __restrict__ edges,
                       float* __restrict__ cfac8, int E, int N,
                       const int* __restrict__ flagp){
  int e = blockIdx.x * 256 + threadIdx.x;
  if (e >= E) return;
  int isf32 = *flagp;
  int s_ = src[e], d_ = dst[e];
  float nrm = dinv[s_] * ldf(w, e, isf32) * dinv[d_];
  int b = blockIdx.x & 7;                          // same mapping as k_pass1
  unsigned sb = (unsigned)((sbasePk[d_] >> (8 * b)) & 0xFFu);
  int pos = rowptr[d_] + (int)sb + (int)rank[e];
  if (pos >= E) pos = E - 1;                       // memory-safety clamp
  edges[pos] = make_int2(s_, __float_as_int(nrm));
  atomicAdd(&cfac8[(size_t)b * N + s_], nrm);      // no-return, shadowed
}

// ---------- merge cfac shadows + self term ----------
__global__ void k_cfacm(const float* __restrict__ cfac8, const float* __restrict__ dinv,
                        float* __restrict__ cfac, int N){
  int i = blockIdx.x * 256 + threadIdx.x;
  if (i >= N) return;
  float di = dinv[i];
  float c = di * di;
  #pragma unroll
  for (int b = 0; b < 8; ++b) c += cfac8[(size_t)b * N + i];
  cfac[i] = c;
}

// ---------- W1T[n*128+k] = W1[k*128+n], canonical bf16 ----------
__global__ void k_transpose(const void* __restrict__ W1, unsigned short* __restrict__ W1T,
                            const int* __restrict__ flagp){
  int gid = blockIdx.x * 256 + threadIdx.x;
  int isf32 = *flagp;
  int k = gid & 127, n = gid >> 7;
  W1T[gid] = isf32 ? f2bf(((const float*)W1)[k * 128 + n])
                   : ((const unsigned short*)W1)[k * 128 + n];
}

// ---------- H = x @ W1, bf16 MFMA 16x16x32, one wave = 16 rows x 128 cols ----------
__global__ void __launch_bounds__(256) k_gemm(const void* __restrict__ xv,
                                              const __bf16* __restrict__ wt,
                                              unsigned short* __restrict__ H, int N,
                                              const int* __restrict__ flagp){
  int wave = (blockIdx.x * blockDim.x + threadIdx.x) >> 6;
  int lane = threadIdx.x & 63;
  int row16 = wave << 4;
  if (row16 >= N) return;
  int isf32 = *flagp;
  int m = lane & 15, q = lane >> 4;
  bf16x8 a0, a1, a2, a3;
  if (isf32){
    const float* ap = (const float*)xv + (size_t)(row16 + m) * 128 + q * 8;
    #pragma unroll
    for (int j = 0; j < 8; ++j){
      a0[j] = us2bf(f2bf(ap[j +  0]));
      a1[j] = us2bf(f2bf(ap[j + 32]));
      a2[j] = us2bf(f2bf(ap[j + 64]));
      a3[j] = us2bf(f2bf(ap[j + 96]));
    }
  } else {
    const __bf16* ap = (const __bf16*)xv + (size_t)(row16 + m) * 128 + q * 8;
    a0 = *(const bf16x8*)(ap +  0);
    a1 = *(const bf16x8*)(ap + 32);
    a2 = *(const bf16x8*)(ap + 64);
    a3 = *(const bf16x8*)(ap + 96);
  }
  for (int nt = 0; nt < 8; ++nt){
    const __bf16* bp = wt + (size_t)(nt * 16 + m) * 128 + q * 8;
    bf16x8 b0 = *(const bf16x8*)(bp +  0);
    bf16x8 b1 = *(const bf16x8*)(bp + 32);
    bf16x8 b2 = *(const bf16x8*)(bp + 64);
    bf16x8 b3 = *(const bf16x8*)(bp + 96);
    f32x4 acc = {0.f, 0.f, 0.f, 0.f};
    acc = __builtin_amdgcn_mfma_f32_16x16x32_bf16(a0, b0, acc, 0, 0, 0);
    acc = __builtin_amdgcn_mfma_f32_16x16x32_bf16(a1, b1, acc, 0, 0, 0);
    acc = __builtin_amdgcn_mfma_f32_16x16x32_bf16(a2, b2, acc, 0, 0, 0);
    acc = __builtin_amdgcn_mfma_f32_16x16x32_bf16(a3, b3, acc, 0, 0, 0);
    unsigned short* op = H + (size_t)(row16 + q * 4) * 128 + nt * 16 + m;
    op[0]   = f2bf(acc[0]);
    op[128] = f2bf(acc[1]);
    op[256] = f2bf(acc[2]);
    op[384] = f2bf(acc[3]);
  }
}

// ---------- quarter-wave aggregation: 16 lanes x 8 feats per H row, 4 edges/step,
//            2-deep unroll; shfl-reduce across groups; relu; c-weighted sum -> v ----------
__global__ void __launch_bounds__(256) k_agg(const unsigned short* __restrict__ H,
    const int* __restrict__ rowptr, const int* __restrict__ cnt,
    const int2* __restrict__ edges, const float* __restrict__ dinv,
    const float* __restrict__ cfac, const void* __restrict__ b1,
    float* __restrict__ v, int N, int totw, const int* __restrict__ flagp){
  __shared__ float vsh[128];
  int tid = threadIdx.x;
  if (tid < 128) vsh[tid] = 0.0f;
  __syncthreads();
  int isf32 = *flagp;
  int lane = tid & 63;
  int g = lane >> 4;                 // group 0..3 (edge slot)
  int i = lane & 15;                 // feature sixteenth: feats i*8 .. i*8+7
  int gwave = (blockIdx.x * blockDim.x + tid) >> 6;
  float bx[8];
  #pragma unroll
  for (int j = 0; j < 8; ++j) bx[j] = ldf(b1, i * 8 + j, isf32);
  float ax[8] = {0,0,0,0,0,0,0,0};
  for (int d = gwave; d < N; d += totw){
    int start = rowptr[d];
    int num   = cnt[d];
    float di  = dinv[d];
    float cf  = cfac[d];
    float acc[8] = {0,0,0,0,0,0,0,0};
    uint4 hs = *(const uint4*)(H + (size_t)d * 128 + i * 8);
    fma8(acc, (g == 0) ? di * di : 0.0f, hs);        // self-loop term (group 0 only)
    int p = start, pe = start + num;
    while (p < pe){
      int p0 = p + g, p1 = p + 4 + g;
      bool v0 = p0 < pe, v1 = p1 < pe;
      int2 r0 = v0 ? edges[p0] : make_int2(0, 0);
      int2 r1 = v1 ? edges[p1] : make_int2(0, 0);
      uint4 h0 = *(const uint4*)(H + (size_t)r0.x * 128 + i * 8);
      uint4 h1 = *(const uint4*)(H + (size_t)r1.x * 128 + i * 8);
      fma8(acc, v0 ? __int_as_float(r0.y) : 0.0f, h0);
      fma8(acc, v1 ? __int_as_float(r1.y) : 0.0f, h1);
      p += 8;
    }
    #pragma unroll
    for (int j = 0; j < 8; ++j){
      acc[j] += __shfl_xor(acc[j], 16);
      acc[j] += __shfl_xor(acc[j], 32);
    }
    if (g == 0){
      #pragma unroll
      for (int j = 0; j < 8; ++j){
        float r = fmaxf(acc[j] + bx[j], 0.0f);
        ax[j] = fmaf(cf, r, ax[j]);
      }
    }
  }
  if (g == 0){
    #pragma unroll
    for (int j = 0; j < 8; ++j) atomicAdd(&vsh[i * 8 + j], ax[j]);
  }
  __syncthreads();
  if (tid < 128) atomicAdd(&v[tid], vsh[tid]);
}

// ---------- tiny head ----------
__global__ void __launch_bounds__(128) k_head(const float* __restrict__ v,
    const void* __restrict__ W2, const void* __restrict__ b2,
    const void* __restrict__ Wmu, const void* __restrict__ bmu,
    const void* __restrict__ Wlv, const void* __restrict__ blv,
    void* __restrict__ outv, float invN, const int* __restrict__ flagp){
  __shared__ float gsh[128];
  __shared__ float tsh[128];
  int t = threadIdx.x;
  int isf32 = *flagp;
  gsh[t] = v[t] * invN;
  __syncthreads();
  float acc = ldf(b2, t, isf32);
  for (int k = 0; k < 128; ++k) acc = fmaf(gsh[k], ldf(W2, k * 128 + t, isf32), acc);
  tsh[t] = acc;
  __syncthreads();
  int j = t & 63;
  const void* Wp = (t < 64) ? Wmu : Wlv;
  float o = ldf((t < 64) ? bmu : blv, j, isf32);
  for (int k = 0; k < 128; ++k) o = fmaf(tsh[k], ldf(Wp, k * 64 + j, isf32), o);
  if (isf32) ((float*)outv)[t] = o;
  else       ((unsigned short*)outv)[t] = f2bf(o);
}

extern "C" void kernel_launch(void* const* d_in, const int* in_sizes, int n_in,
                              void* d_out, int out_size, void* d_ws, size_t ws_size,
                              hipStream_t stream) {
  const void* x   = d_in[0];
  const int*  ei  = (const int*)d_in[1];
  const void* w   = d_in[2];
  const void* W1  = d_in[3];
  const void* b1  = d_in[4];
  const void* W2  = d_in[5];
  const void* b2  = d_in[6];
  const void* Wmu = d_in[7];
  const void* bmu = d_in[8];
  const void* Wlv = d_in[9];
  const void* blv = d_in[10];

  const int N = in_sizes[0] / 128;     // 100000
  const int E = in_sizes[2];           // 1600000
  const int* src = ei;
  const int* dst = ei + E;

  char* wsb = (char*)d_ws;
  size_t off = 0;
  auto alloc = [&](size_t bytes) -> void* {
    off = (off + 255) & ~(size_t)255;
    void* p = wsb + off;
    off += bytes;
    return p;
  };
  int*   flag     = (int*)  alloc(16);
  float* dinv     = (float*)alloc((size_t)N * 4);
  int*   cnt      = (int*)  alloc((size_t)N * 4);
  int*   rowptr   = (int*)  alloc((size_t)(N + 1) * 4);
  float* cfac     = (float*)alloc((size_t)N * 4);
  u64*   sbasePk  = (u64*)  alloc((size_t)N * 8);
  int*   bsum     = (int*)  alloc(512 * 4);
  int*   boffs    = (int*)  alloc(512 * 4);
  float* v        = (float*)alloc(128 * 4);
  unsigned short* W1T = (unsigned short*)alloc(128 * 128 * 2);
  float* cfac8    = (float*)alloc((size_t)N * 8 * 4);
  int2*  edges    = (int2*) alloc((size_t)E * 8);
  // regionA: phase-1 {dc8 (N*8*8) | rank (E*4)} overlaid by phase-2 H (N*128*2).
  // Safe: dc8 dead after k_dinv, rank dead after k_fill, H written by k_gemm
  // which launches after both (stream-ordered).
  size_t dc8_b  = (size_t)N * 8 * 8;
  size_t rank_b = (size_t)E * 4;
  size_t H_b    = (size_t)N * 128 * 2;
  size_t regA   = dc8_b + rank_b > H_b ? dc8_b + rank_b : H_b;
  char* regionA = (char*)alloc(regA);
  u64*      dc8  = (u64*)regionA;
  unsigned* rank = (unsigned*)(regionA + dc8_b);
  unsigned short* H = (unsigned short*)regionA;
  (void)ws_size; (void)n_in; (void)out_size;

  const int nb_n = (N + 255) / 256;    // 391
  const int nb_e = (E + 255) / 256;    // 6250

  k_detect<<<1, 256, 0, stream>>>((const unsigned*)x, flag);
  k_init<<<nb_n, 256, 0, stream>>>(dc8, cfac8, v, N);
  k_pass1<<<nb_e, 256, 0, stream>>>(dst, w, dc8, rank, E, N, flag);
  k_dinv<<<nb_n, 256, 0, stream>>>(dc8, dinv, cnt, sbasePk, N);
  k_scanA<<<nb_n, 256, 0, stream>>>(cnt, rowptr, bsum, N);
  k_scanB<<<1, 512, 0, stream>>>(bsum, boffs, nb_n);
  k_scanC<<<nb_n, 256, 0, stream>>>(rowptr, boffs, N);
  k_fill<<<nb_e, 256, 0, stream>>>(src, dst, w, dinv, rowptr, sbasePk, rank,
                                   edges, cfac8, E, N, flag);
  k_cfacm<<<nb_n, 256, 0, stream>>>(cfac8, dinv, cfac, N);
  k_transpose<<<64, 256, 0, stream>>>(W1, W1T, flag);
  const int nwaves = (N + 15) / 16;
  const int nb_g = (nwaves + 3) / 4;
  k_gemm<<<nb_g, 256, 0, stream>>>(x, (const __bf16*)W1T, H, N, flag);
  const int nb_agg = 4096;
  k_agg<<<nb_agg, 256, 0, stream>>>(H, rowptr, cnt, edges, dinv, cfac, b1, v, N,
                                    nb_agg * 256 / 64, flag);
  k_head<<<1, 128, 0, stream>>>(v, W2, b2, Wmu, bmu, Wlv, blv,
                                d_out, 1.0f / (float)N, flag);
}

// Round 4
// 471.403 us; speedup vs baseline: 1.2965x; 1.0425x over previous
//
#include <hip/hip_runtime.h>

// SpectralGNNEncoder on MI355X.
// out = (mu, logvar):
//   h1 = relu(Agg1(x@W1) + b1)   (sym-norm scatter-add w/ self loops)
//   g  = mean(Agg2(h1@W2)) + b2 = ((1/N) c^T h1) @ W2 + b2,  c[i]=dinv[i]^2+sum_{src=i} norm
// Round 4: H stored as fp8-e4m3 (gather traffic 256->128 B/edge; L2-resident 12.8 MB),
// 4-byte packed edges (src:17|norm:15), ushort rank. k_agg is miss-traffic-bound at
// ~1.4 TB/s random-line fabric ceiling -> halve the bytes.

typedef __bf16 bf16x8 __attribute__((ext_vector_type(8)));
typedef float f32x4 __attribute__((ext_vector_type(4)));
typedef float f32x2 __attribute__((ext_vector_type(2)));
typedef unsigned long long u64;

__device__ __forceinline__ float bf2f(unsigned short u){
  return __uint_as_float(((unsigned)u) << 16);
}
__device__ __forceinline__ unsigned short f2bf(float f){
  unsigned u = __float_as_uint(f);
  u += 0x7fffu + ((u >> 16) & 1u);   // RNE
  return (unsigned short)(u >> 16);
}
__device__ __forceinline__ __bf16 us2bf(unsigned short u){
  __bf16 b; __builtin_memcpy(&b, &u, 2); return b;
}
__device__ __forceinline__ float ldf(const void* p, int i, int isf32){
  return isf32 ? ((const float*)p)[i] : bf2f(((const unsigned short*)p)[i]);
}
// fma 8 fp8 feats (packed in uint2) into acc[8]
__device__ __forceinline__ void fma8f8(float* acc, float n, uint2 h){
  f32x2 p0 = __builtin_amdgcn_cvt_pk_f32_fp8((int)h.x, false);
  f32x2 p1 = __builtin_amdgcn_cvt_pk_f32_fp8((int)h.x, true);
  f32x2 p2 = __builtin_amdgcn_cvt_pk_f32_fp8((int)h.y, false);
  f32x2 p3 = __builtin_amdgcn_cvt_pk_f32_fp8((int)h.y, true);
  acc[0] = fmaf(n, p0[0], acc[0]);
  acc[1] = fmaf(n, p0[1], acc[1]);
  acc[2] = fmaf(n, p1[0], acc[2]);
  acc[3] = fmaf(n, p1[1], acc[3]);
  acc[4] = fmaf(n, p2[0], acc[4]);
  acc[5] = fmaf(n, p2[1], acc[5]);
  acc[6] = fmaf(n, p3[0], acc[6]);
  acc[7] = fmaf(n, p3[1], acc[7]);
}

// ---------- dtype sniffer: flag=1 iff float tensors are f32 ----------
__global__ void k_detect(const unsigned* __restrict__ xw, int* __restrict__ flag){
  __shared__ int s[256];
  int t = threadIdx.x;
  int cnt = 0;
  for (int i = t; i < 4096; i += 256){
    unsigned lo = xw[i] & 0xFFFFu;
    int e = (int)((lo >> 7) & 0xFFu);
    if ((e >= 100 && e <= 141) || (lo & 0x7FFFu) == 0) cnt++;
  }
  s[t] = cnt;
  __syncthreads();
  for (int off = 128; off > 0; off >>= 1){
    if (t < off) s[t] += s[t + off];
    __syncthreads();
  }
  if (t == 0) *flag = (s[0] < 2458) ? 1 : 0;
}

// ---------- init: zero shadowed accumulators + v ----------
__global__ void k_init(u64* __restrict__ dc8, float* __restrict__ cfac8,
                       float* __restrict__ v, int N){
  int i = blockIdx.x * 256 + threadIdx.x;
  if (i < N){
    #pragma unroll
    for (int b = 0; b < 8; ++b){
      dc8[(size_t)b * N + i] = 0ull;
      cfac8[(size_t)b * N + i] = 0.0f;
    }
  }
  if (i < 128) v[i] = 0.0f;
}

// ---------- pass1: one u64 atomic = deg(fixed-point) + cnt; old>>40 = rank ----------
__global__ void k_pass1(const int* __restrict__ dst, const void* __restrict__ w,
                        u64* __restrict__ dc8, unsigned short* __restrict__ rank,
                        int E, int N, const int* __restrict__ flagp){
  int e = blockIdx.x * 256 + threadIdx.x;
  if (e >= E) return;
  int isf32 = *flagp;
  int d = dst[e];
  float wv = ldf(w, e, isf32);
  u64 wfix = (u64)(wv * 65536.0f + 0.5f);          // 2^-16 fixed point
  int b = blockIdx.x & 7;                          // shadow = XCD-ish
  u64 old = atomicAdd(&dc8[(size_t)b * N + d], (1ull << 40) | wfix);
  rank[e] = (unsigned short)(old >> 40);
}

// ---------- merge shadows: dinv, cnt, packed per-shadow prefix bytes ----------
__global__ void k_dinv(const u64* __restrict__ dc8, float* __restrict__ dinv,
                       int* __restrict__ cnt, u64* __restrict__ sbasePk, int N){
  int i = blockIdx.x * 256 + threadIdx.x;
  if (i >= N) return;
  unsigned sb = 0;
  u64 degfix = 0, pk = 0;
  #pragma unroll
  for (int b = 0; b < 8; ++b){
    u64 dcb = dc8[(size_t)b * N + i];
    pk |= ((u64)(sb & 0xFFu)) << (8 * b);          // exclusive prefix for shadow b
    sb += (unsigned)(dcb >> 40);
    degfix += dcb & 0xFFFFFFFFFFull;
  }
  float deg = 1.0f + (float)degfix * (1.0f / 65536.0f);  // +1 self loop
  dinv[i] = rsqrtf(deg);
  cnt[i] = (int)sb;
  sbasePk[i] = pk;
}

// ---------- exclusive scan of cnt -> rowptr ----------
__global__ void k_scanA(const int* __restrict__ cnt, int* __restrict__ rowptr,
                        int* __restrict__ bsum, int N){
  __shared__ int s[256];
  int i = blockIdx.x * 256 + threadIdx.x;
  int val = (i < N) ? cnt[i] : 0;
  s[threadIdx.x] = val;
  __syncthreads();
  for (int off = 1; off < 256; off <<= 1){
    int tmp = (threadIdx.x >= off) ? s[threadIdx.x - off] : 0;
    __syncthreads();
    s[threadIdx.x] += tmp;
    __syncthreads();
  }
  if (i < N) rowptr[i] = s[threadIdx.x] - val;
  if (threadIdx.x == 255) bsum[blockIdx.x] = s[255];
}

__global__ void k_scanB(const int* __restrict__ bsum, int* __restrict__ boffs, int NB){
  __shared__ int s[512];
  int t = threadIdx.x;
  int val = (t < NB) ? bsum[t] : 0;
  s[t] = val;
  __syncthreads();
  for (int off = 1; off < 512; off <<= 1){
    int tmp = (t >= off) ? s[t - off] : 0;
    __syncthreads();
    s[t] += tmp;
    __syncthreads();
  }
  boffs[t] = s[t] - val;
}

__global__ void k_scanC(int* __restrict__ rowptr, const int* __restrict__ boffs, int N){
  int i = blockIdx.x * 256 + threadIdx.x;
  if (i >= N) return;
  rowptr[i] += boffs[blockIdx.x];
}

// ---------- fill CSR: zero returning atomics; 4B packed edges; shadowed cfac ----------
__global__ void k_fill(const int* __restrict__ src, const int* __restrict__ dst,
                       const void* __restrict__ w, const float* __restrict__ dinv,
                       const int* __restrict__ rowptr, const u64* __restrict__ sbasePk,
                       const unsigned short* __restrict__ rank, unsigned* __restrict__ edges,
                       float* __restrict__ cfac8, int E, int N,
                       const int* __restrict__ flagp){
  int e = blockIdx.x * 256 + threadIdx.x;
  if (e >= E) return;
  int isf32 = *flagp;
  int s_ = src[e], d_ = dst[e];
  float nrm = dinv[s_] * ldf(w, e, isf32) * dinv[d_];
  int nq = (int)(nrm * 32768.0f + 0.5f);
  if (nq > 32767) nq = 32767;
  int b = blockIdx.x & 7;                          // same mapping as k_pass1
  unsigned sb = (unsigned)((sbasePk[d_] >> (8 * b)) & 0xFFu);
  int pos = rowptr[d_] + (int)sb + (int)rank[e];
  if (pos >= E) pos = E - 1;                       // memory-safety clamp
  edges[pos] = ((unsigned)s_ << 15) | (unsigned)nq;
  atomicAdd(&cfac8[(size_t)b * N + s_], nrm);      // no-return, shadowed
}

// ---------- merge cfac shadows + self term ----------
__global__ void k_cfacm(const float* __restrict__ cfac8, const float* __restrict__ dinv,
                        float* __restrict__ cfac, int N){
  int i = blockIdx.x * 256 + threadIdx.x;
  if (i >= N) return;
  float di = dinv[i];
  float c = di * di;
  #pragma unroll
  for (int b = 0; b < 8; ++b) c += cfac8[(size_t)b * N + i];
  cfac[i] = c;
}

// ---------- W1T[n*128+k] = W1[k*128+n], canonical bf16 ----------
__global__ void k_transpose(const void* __restrict__ W1, unsigned short* __restrict__ W1T,
                            const int* __restrict__ flagp){
  int gid = blockIdx.x * 256 + threadIdx.x;
  int isf32 = *flagp;
  int k = gid & 127, n = gid >> 7;
  W1T[gid] = isf32 ? f2bf(((const float*)W1)[k * 128 + n])
                   : ((const unsigned short*)W1)[k * 128 + n];
}

// ---------- H = x @ W1 (bf16 MFMA), epilogue stores fp8-e4m3 ----------
__global__ void __launch_bounds__(256) k_gemm(const void* __restrict__ xv,
                                              const __bf16* __restrict__ wt,
                                              unsigned char* __restrict__ H, int N,
                                              const int* __restrict__ flagp){
  int wave = (blockIdx.x * blockDim.x + threadIdx.x) >> 6;
  int lane = threadIdx.x & 63;
  int row16 = wave << 4;
  if (row16 >= N) return;
  int isf32 = *flagp;
  int m = lane & 15, q = lane >> 4;
  bf16x8 a0, a1, a2, a3;
  if (isf32){
    const float* ap = (const float*)xv + (size_t)(row16 + m) * 128 + q * 8;
    #pragma unroll
    for (int j = 0; j < 8; ++j){
      a0[j] = us2bf(f2bf(ap[j +  0]));
      a1[j] = us2bf(f2bf(ap[j + 32]));
      a2[j] = us2bf(f2bf(ap[j + 64]));
      a3[j] = us2bf(f2bf(ap[j + 96]));
    }
  } else {
    const __bf16* ap = (const __bf16*)xv + (size_t)(row16 + m) * 128 + q * 8;
    a0 = *(const bf16x8*)(ap +  0);
    a1 = *(const bf16x8*)(ap + 32);
    a2 = *(const bf16x8*)(ap + 64);
    a3 = *(const bf16x8*)(ap + 96);
  }
  for (int nt = 0; nt < 8; ++nt){
    const __bf16* bp = wt + (size_t)(nt * 16 + m) * 128 + q * 8;
    bf16x8 b0 = *(const bf16x8*)(bp +  0);
    bf16x8 b1 = *(const bf16x8*)(bp + 32);
    bf16x8 b2 = *(const bf16x8*)(bp + 64);
    bf16x8 b3 = *(const bf16x8*)(bp + 96);
    f32x4 acc = {0.f, 0.f, 0.f, 0.f};
    acc = __builtin_amdgcn_mfma_f32_16x16x32_bf16(a0, b0, acc, 0, 0, 0);
    acc = __builtin_amdgcn_mfma_f32_16x16x32_bf16(a1, b1, acc, 0, 0, 0);
    acc = __builtin_amdgcn_mfma_f32_16x16x32_bf16(a2, b2, acc, 0, 0, 0);
    acc = __builtin_amdgcn_mfma_f32_16x16x32_bf16(a3, b3, acc, 0, 0, 0);
    // C/D: col=lane&15, row=q*4+r ; store 1 fp8 byte each
    unsigned char* op = H + (size_t)(row16 + q * 4) * 128 + nt * 16 + m;
    op[0]   = (unsigned char)(__builtin_amdgcn_cvt_pk_fp8_f32(acc[0], acc[0], 0, false) & 0xFF);
    op[128] = (unsigned char)(__builtin_amdgcn_cvt_pk_fp8_f32(acc[1], acc[1], 0, false) & 0xFF);
    op[256] = (unsigned char)(__builtin_amdgcn_cvt_pk_fp8_f32(acc[2], acc[2], 0, false) & 0xFF);
    op[384] = (unsigned char)(__builtin_amdgcn_cvt_pk_fp8_f32(acc[3], acc[3], 0, false) & 0xFF);
  }
}

// ---------- quarter-wave aggregation over fp8 H: 16 lanes x 8 feats, 4 edges/step
//            x2 unroll; shfl-reduce; relu; c-weighted sum -> v ----------
__global__ void __launch_bounds__(256) k_agg(const unsigned char* __restrict__ H,
    const int* __restrict__ rowptr, const int* __restrict__ cnt,
    const unsigned* __restrict__ edges, const float* __restrict__ dinv,
    const float* __restrict__ cfac, const void* __restrict__ b1,
    float* __restrict__ v, int N, int totw, const int* __restrict__ flagp){
  __shared__ float vsh[128];
  int tid = threadIdx.x;
  if (tid < 128) vsh[tid] = 0.0f;
  __syncthreads();
  int isf32 = *flagp;
  int lane = tid & 63;
  int g = lane >> 4;                 // group 0..3 (edge slot)
  int i = lane & 15;                 // feature sixteenth: feats i*8 .. i*8+7
  int gwave = (blockIdx.x * blockDim.x + tid) >> 6;
  float bx[8];
  #pragma unroll
  for (int j = 0; j < 8; ++j) bx[j] = ldf(b1, i * 8 + j, isf32);
  float ax[8] = {0,0,0,0,0,0,0,0};
  for (int d = gwave; d < N; d += totw){
    int start = rowptr[d];
    int num   = cnt[d];
    float di  = dinv[d];
    float cf  = cfac[d];
    float acc[8] = {0,0,0,0,0,0,0,0};
    uint2 hs = *(const uint2*)(H + (size_t)d * 128 + i * 8);
    fma8f8(acc, (g == 0) ? di * di : 0.0f, hs);      // self-loop term (group 0 only)
    int p = start, pe = start + num;
    while (p < pe){
      int p0 = p + g, p1 = p + 4 + g;
      bool v0 = p0 < pe, v1 = p1 < pe;
      unsigned r0 = v0 ? edges[p0] : 0u;
      unsigned r1 = v1 ? edges[p1] : 0u;
      uint2 h0 = *(const uint2*)(H + (size_t)(r0 >> 15) * 128 + i * 8);
      uint2 h1 = *(const uint2*)(H + (size_t)(r1 >> 15) * 128 + i * 8);
      float n0 = v0 ? (float)(r0 & 32767u) * (1.0f / 32768.0f) : 0.0f;
      float n1 = v1 ? (float)(r1 & 32767u) * (1.0f / 32768.0f) : 0.0f;
      fma8f8(acc, n0, h0);
      fma8f8(acc, n1, h1);
      p += 8;
    }
    #pragma unroll
    for (int j = 0; j < 8; ++j){
      acc[j] += __shfl_xor(acc[j], 16);
      acc[j] += __shfl_xor(acc[j], 32);
    }
    if (g == 0){
      #pragma unroll
      for (int j = 0; j < 8; ++j){
        float r = fmaxf(acc[j] + bx[j], 0.0f);
        ax[j] = fmaf(cf, r, ax[j]);
      }
    }
  }
  if (g == 0){
    #pragma unroll
    for (int j = 0; j < 8; ++j) atomicAdd(&vsh[i * 8 + j], ax[j]);
  }
  __syncthreads();
  if (tid < 128) atomicAdd(&v[tid], vsh[tid]);
}

// ---------- tiny head ----------
__global__ void __launch_bounds__(128) k_head(const float* __restrict__ v,
    const void* __restrict__ W2, const void* __restrict__ b2,
    const void* __restrict__ Wmu, const void* __restrict__ bmu,
    const void* __restrict__ Wlv, const void* __restrict__ blv,
    void* __restrict__ outv, float invN, const int* __restrict__ flagp){
  __shared__ float gsh[128];
  __shared__ float tsh[128];
  int t = threadIdx.x;
  int isf32 = *flagp;
  gsh[t] = v[t] * invN;
  __syncthreads();
  float acc = ldf(b2, t, isf32);
  for (int k = 0; k < 128; ++k) acc = fmaf(gsh[k], ldf(W2, k * 128 + t, isf32), acc);
  tsh[t] = acc;
  __syncthreads();
  int j = t & 63;
  const void* Wp = (t < 64) ? Wmu : Wlv;
  float o = ldf((t < 64) ? bmu : blv, j, isf32);
  for (int k = 0; k < 128; ++k) o = fmaf(tsh[k], ldf(Wp, k * 64 + j, isf32), o);
  if (isf32) ((float*)outv)[t] = o;
  else       ((unsigned short*)outv)[t] = f2bf(o);
}

extern "C" void kernel_launch(void* const* d_in, const int* in_sizes, int n_in,
                              void* d_out, int out_size, void* d_ws, size_t ws_size,
                              hipStream_t stream) {
  const void* x   = d_in[0];
  const int*  ei  = (const int*)d_in[1];
  const void* w   = d_in[2];
  const void* W1  = d_in[3];
  const void* b1  = d_in[4];
  const void* W2  = d_in[5];
  const void* b2  = d_in[6];
  const void* Wmu = d_in[7];
  const void* bmu = d_in[8];
  const void* Wlv = d_in[9];
  const void* blv = d_in[10];

  const int N = in_sizes[0] / 128;     // 100000
  const int E = in_sizes[2];           // 1600000
  const int* src = ei;
  const int* dst = ei + E;

  char* wsb = (char*)d_ws;
  size_t off = 0;
  auto alloc = [&](size_t bytes) -> void* {
    off = (off + 255) & ~(size_t)255;
    void* p = wsb + off;
    off += bytes;
    return p;
  };
  int*   flag     = (int*)  alloc(16);
  float* dinv     = (float*)alloc((size_t)N * 4);
  int*   cnt      = (int*)  alloc((size_t)N * 4);
  int*   rowptr   = (int*)  alloc((size_t)(N + 1) * 4);
  float* cfac     = (float*)alloc((size_t)N * 4);
  u64*   sbasePk  = (u64*)  alloc((size_t)N * 8);
  int*   bsum     = (int*)  alloc(512 * 4);
  int*   boffs    = (int*)  alloc(512 * 4);
  float* v        = (float*)alloc(128 * 4);
  unsigned short* W1T = (unsigned short*)alloc(128 * 128 * 2);
  float* cfac8    = (float*)alloc((size_t)N * 8 * 4);
  unsigned* edges = (unsigned*)alloc((size_t)E * 4);
  // regionA: phase-1 {dc8 (N*8*8) | rank (E*2)} overlaid by phase-2 H (N*128*1).
  // Safe: dc8 dead after k_dinv, rank dead after k_fill; k_gemm launches after both.
  size_t dc8_b  = (size_t)N * 8 * 8;
  size_t rank_b = (size_t)E * 2;
  size_t H_b    = (size_t)N * 128;
  size_t regA   = dc8_b + rank_b > H_b ? dc8_b + rank_b : H_b;
  char* regionA = (char*)alloc(regA);
  u64*            dc8  = (u64*)regionA;
  unsigned short* rank = (unsigned short*)(regionA + dc8_b);
  unsigned char*  H    = (unsigned char*)regionA;
  (void)ws_size; (void)n_in; (void)out_size;

  const int nb_n = (N + 255) / 256;    // 391
  const int nb_e = (E + 255) / 256;    // 6250

  k_detect<<<1, 256, 0, stream>>>((const unsigned*)x, flag);
  k_init<<<nb_n, 256, 0, stream>>>(dc8, cfac8, v, N);
  k_pass1<<<nb_e, 256, 0, stream>>>(dst, w, dc8, rank, E, N, flag);
  k_dinv<<<nb_n, 256, 0, stream>>>(dc8, dinv, cnt, sbasePk, N);
  k_scanA<<<nb_n, 256, 0, stream>>>(cnt, rowptr, bsum, N);
  k_scanB<<<1, 512, 0, stream>>>(bsum, boffs, nb_n);
  k_scanC<<<nb_n, 256, 0, stream>>>(rowptr, boffs, N);
  k_fill<<<nb_e, 256, 0, stream>>>(src, dst, w, dinv, rowptr, sbasePk, rank,
                                   edges, cfac8, E, N, flag);
  k_cfacm<<<nb_n, 256, 0, stream>>>(cfac8, dinv, cfac, N);
  k_transpose<<<64, 256, 0, stream>>>(W1, W1T, flag);
  const int nwaves = (N + 15) / 16;
  const int nb_g = (nwaves + 3) / 4;
  k_gemm<<<nb_g, 256, 0, stream>>>(x, (const __bf16*)W1T, H, N, flag);
  const int nb_agg = 4096;
  k_agg<<<nb_agg, 256, 0, stream>>>(H, rowptr, cnt, edges, dinv, cfac, b1, v, N,
                                    nb_agg * 256 / 64, flag);
  k_head<<<1, 128, 0, stream>>>(v, W2, b2, Wmu, bmu, Wlv, blv,
                                d_out, 1.0f / (float)N, flag);
}

// Round 5
// 419.008 us; speedup vs baseline: 1.4586x; 1.1250x over previous
//
#include <hip/hip_runtime.h>

// SpectralGNNEncoder on MI355X.
// out = (mu, logvar):
//   h1 = relu(Agg1(x@W1) + b1)   (sym-norm scatter-add w/ self loops)
//   g  = mean(Agg2(h1@W2)) + b2 = ((1/N) c^T h1) @ W2 + b2,  c[i]=dinv[i]^2+sum_{src=i} norm
// Round 5: k_agg rebuilt as XCD-sliced (4 fp8 feature-planes of 32 feats = 3.2 MB,
// L2-resident per XCD via blockIdx%8 pinning) with 16 independent per-slot node
// chains per wave (latency hiding by chain parallelism, no per-node shuffles).

typedef __bf16 bf16x8 __attribute__((ext_vector_type(8)));
typedef float f32x4 __attribute__((ext_vector_type(4)));
typedef float f32x2 __attribute__((ext_vector_type(2)));
typedef unsigned long long u64;

__device__ __forceinline__ float bf2f(unsigned short u){
  return __uint_as_float(((unsigned)u) << 16);
}
__device__ __forceinline__ unsigned short f2bf(float f){
  unsigned u = __float_as_uint(f);
  u += 0x7fffu + ((u >> 16) & 1u);   // RNE
  return (unsigned short)(u >> 16);
}
__device__ __forceinline__ __bf16 us2bf(unsigned short u){
  __bf16 b; __builtin_memcpy(&b, &u, 2); return b;
}
__device__ __forceinline__ float ldf(const void* p, int i, int isf32){
  return isf32 ? ((const float*)p)[i] : bf2f(((const unsigned short*)p)[i]);
}
// fma 8 fp8 feats (packed in uint2) into acc[8]
__device__ __forceinline__ void fma8f8(float* acc, float n, uint2 h){
  f32x2 p0 = __builtin_amdgcn_cvt_pk_f32_fp8((int)h.x, false);
  f32x2 p1 = __builtin_amdgcn_cvt_pk_f32_fp8((int)h.x, true);
  f32x2 p2 = __builtin_amdgcn_cvt_pk_f32_fp8((int)h.y, false);
  f32x2 p3 = __builtin_amdgcn_cvt_pk_f32_fp8((int)h.y, true);
  acc[0] = fmaf(n, p0[0], acc[0]);
  acc[1] = fmaf(n, p0[1], acc[1]);
  acc[2] = fmaf(n, p1[0], acc[2]);
  acc[3] = fmaf(n, p1[1], acc[3]);
  acc[4] = fmaf(n, p2[0], acc[4]);
  acc[5] = fmaf(n, p2[1], acc[5]);
  acc[6] = fmaf(n, p3[0], acc[6]);
  acc[7] = fmaf(n, p3[1], acc[7]);
}

// ---------- dtype sniffer: flag=1 iff float tensors are f32 ----------
__global__ void k_detect(const unsigned* __restrict__ xw, int* __restrict__ flag){
  __shared__ int s[256];
  int t = threadIdx.x;
  int cnt = 0;
  for (int i = t; i < 4096; i += 256){
    unsigned lo = xw[i] & 0xFFFFu;
    int e = (int)((lo >> 7) & 0xFFu);
    if ((e >= 100 && e <= 141) || (lo & 0x7FFFu) == 0) cnt++;
  }
  s[t] = cnt;
  __syncthreads();
  for (int off = 128; off > 0; off >>= 1){
    if (t < off) s[t] += s[t + off];
    __syncthreads();
  }
  if (t == 0) *flag = (s[0] < 2458) ? 1 : 0;
}

// ---------- init: zero shadowed accumulators + v ----------
__global__ void k_init(u64* __restrict__ dc8, float* __restrict__ cfac8,
                       float* __restrict__ v, int N){
  int i = blockIdx.x * 256 + threadIdx.x;
  if (i < N){
    #pragma unroll
    for (int b = 0; b < 8; ++b){
      dc8[(size_t)b * N + i] = 0ull;
      cfac8[(size_t)b * N + i] = 0.0f;
    }
  }
  if (i < 128) v[i] = 0.0f;
}

// ---------- pass1: one u64 atomic = deg(fixed-point) + cnt; old>>40 = rank ----------
__global__ void k_pass1(const int* __restrict__ dst, const void* __restrict__ w,
                        u64* __restrict__ dc8, unsigned short* __restrict__ rank,
                        int E, int N, const int* __restrict__ flagp){
  int e = blockIdx.x * 256 + threadIdx.x;
  if (e >= E) return;
  int isf32 = *flagp;
  int d = dst[e];
  float wv = ldf(w, e, isf32);
  u64 wfix = (u64)(wv * 65536.0f + 0.5f);          // 2^-16 fixed point
  int b = blockIdx.x & 7;                          // shadow = XCD
  u64 old = atomicAdd(&dc8[(size_t)b * N + d], (1ull << 40) | wfix);
  rank[e] = (unsigned short)(old >> 40);
}

// ---------- merge shadows: dinv, cnt, packed per-shadow prefix bytes ----------
__global__ void k_dinv(const u64* __restrict__ dc8, float* __restrict__ dinv,
                       int* __restrict__ cnt, u64* __restrict__ sbasePk, int N){
  int i = blockIdx.x * 256 + threadIdx.x;
  if (i >= N) return;
  unsigned sb = 0;
  u64 degfix = 0, pk = 0;
  #pragma unroll
  for (int b = 0; b < 8; ++b){
    u64 dcb = dc8[(size_t)b * N + i];
    pk |= ((u64)(sb & 0xFFu)) << (8 * b);          // exclusive prefix for shadow b
    sb += (unsigned)(dcb >> 40);
    degfix += dcb & 0xFFFFFFFFFFull;
  }
  float deg = 1.0f + (float)degfix * (1.0f / 65536.0f);  // +1 self loop
  dinv[i] = rsqrtf(deg);
  cnt[i] = (int)sb;
  sbasePk[i] = pk;
}

// ---------- exclusive scan of cnt -> rowptr ----------
__global__ void k_scanA(const int* __restrict__ cnt, int* __restrict__ rowptr,
                        int* __restrict__ bsum, int N){
  __shared__ int s[256];
  int i = blockIdx.x * 256 + threadIdx.x;
  int val = (i < N) ? cnt[i] : 0;
  s[threadIdx.x] = val;
  __syncthreads();
  for (int off = 1; off < 256; off <<= 1){
    int tmp = (threadIdx.x >= off) ? s[threadIdx.x - off] : 0;
    __syncthreads();
    s[threadIdx.x] += tmp;
    __syncthreads();
  }
  if (i < N) rowptr[i] = s[threadIdx.x] - val;
  if (threadIdx.x == 255) bsum[blockIdx.x] = s[255];
}

__global__ void k_scanB(const int* __restrict__ bsum, int* __restrict__ boffs, int NB){
  __shared__ int s[512];
  int t = threadIdx.x;
  int val = (t < NB) ? bsum[t] : 0;
  s[t] = val;
  __syncthreads();
  for (int off = 1; off < 512; off <<= 1){
    int tmp = (t >= off) ? s[t - off] : 0;
    __syncthreads();
    s[t] += tmp;
    __syncthreads();
  }
  boffs[t] = s[t] - val;
}

__global__ void k_scanC(int* __restrict__ rowptr, const int* __restrict__ boffs, int N){
  int i = blockIdx.x * 256 + threadIdx.x;
  if (i >= N) return;
  rowptr[i] += boffs[blockIdx.x];
}

// ---------- fill CSR: zero returning atomics; 4B packed edges (NT store) ----------
__global__ void k_fill(const int* __restrict__ src, const int* __restrict__ dst,
                       const void* __restrict__ w, const float* __restrict__ dinv,
                       const int* __restrict__ rowptr, const u64* __restrict__ sbasePk,
                       const unsigned short* __restrict__ rank, unsigned* __restrict__ edges,
                       float* __restrict__ cfac8, int E, int N,
                       const int* __restrict__ flagp){
  int e = blockIdx.x * 256 + threadIdx.x;
  if (e >= E) return;
  int isf32 = *flagp;
  int s_ = src[e], d_ = dst[e];
  float nrm = dinv[s_] * ldf(w, e, isf32) * dinv[d_];
  int nq = (int)(nrm * 32768.0f + 0.5f);
  if (nq > 32767) nq = 32767;
  int b = blockIdx.x & 7;                          // same mapping as k_pass1
  unsigned sb = (unsigned)((sbasePk[d_] >> (8 * b)) & 0xFFu);
  int pos = rowptr[d_] + (int)sb + (int)rank[e];
  if (pos >= E) pos = E - 1;                       // memory-safety clamp
  __builtin_nontemporal_store(((unsigned)s_ << 15) | (unsigned)nq, &edges[pos]);
  atomicAdd(&cfac8[(size_t)b * N + s_], nrm);      // no-return, shadowed
}

// ---------- merge cfac shadows; pack per-node (dinv^2, cfac) and (rowptr, cnt) ----------
__global__ void k_cfacm(const float* __restrict__ cfac8, const float* __restrict__ dinv,
                        const int* __restrict__ rowptr, const int* __restrict__ cnt,
                        float2* __restrict__ dc, int2* __restrict__ rc, int N){
  int i = blockIdx.x * 256 + threadIdx.x;
  if (i >= N) return;
  float di = dinv[i];
  float c = di * di;
  #pragma unroll
  for (int b = 0; b < 8; ++b) c += cfac8[(size_t)b * N + i];
  dc[i] = make_float2(di * di, c);
  rc[i] = make_int2(rowptr[i], cnt[i]);
}

// ---------- W1T[n*128+k] = W1[k*128+n], canonical bf16 ----------
__global__ void k_transpose(const void* __restrict__ W1, unsigned short* __restrict__ W1T,
                            const int* __restrict__ flagp){
  int gid = blockIdx.x * 256 + threadIdx.x;
  int isf32 = *flagp;
  int k = gid & 127, n = gid >> 7;
  W1T[gid] = isf32 ? f2bf(((const float*)W1)[k * 128 + n])
                   : ((const unsigned short*)W1)[k * 128 + n];
}

// ---------- H = x @ W1 (bf16 MFMA); epilogue stores fp8 in 4 plane-major slices:
//            plane p holds feats [p*32, p*32+32) as H[p*N*32 + node*32 + f] ----------
__global__ void __launch_bounds__(256) k_gemm(const void* __restrict__ xv,
                                              const __bf16* __restrict__ wt,
                                              unsigned char* __restrict__ H, int N,
                                              const int* __restrict__ flagp){
  int wave = (blockIdx.x * blockDim.x + threadIdx.x) >> 6;
  int lane = threadIdx.x & 63;
  int row16 = wave << 4;
  if (row16 >= N) return;
  int isf32 = *flagp;
  int m = lane & 15, q = lane >> 4;
  size_t planeStride = (size_t)N * 32;
  bf16x8 a0, a1, a2, a3;
  if (isf32){
    const float* ap = (const float*)xv + (size_t)(row16 + m) * 128 + q * 8;
    #pragma unroll
    for (int j = 0; j < 8; ++j){
      a0[j] = us2bf(f2bf(ap[j +  0]));
      a1[j] = us2bf(f2bf(ap[j + 32]));
      a2[j] = us2bf(f2bf(ap[j + 64]));
      a3[j] = us2bf(f2bf(ap[j + 96]));
    }
  } else {
    const __bf16* ap = (const __bf16*)xv + (size_t)(row16 + m) * 128 + q * 8;
    a0 = *(const bf16x8*)(ap +  0);
    a1 = *(const bf16x8*)(ap + 32);
    a2 = *(const bf16x8*)(ap + 64);
    a3 = *(const bf16x8*)(ap + 96);
  }
  for (int nt = 0; nt < 8; ++nt){
    const __bf16* bp = wt + (size_t)(nt * 16 + m) * 128 + q * 8;
    bf16x8 b0 = *(const bf16x8*)(bp +  0);
    bf16x8 b1 = *(const bf16x8*)(bp + 32);
    bf16x8 b2 = *(const bf16x8*)(bp + 64);
    bf16x8 b3 = *(const bf16x8*)(bp + 96);
    f32x4 acc = {0.f, 0.f, 0.f, 0.f};
    acc = __builtin_amdgcn_mfma_f32_16x16x32_bf16(a0, b0, acc, 0, 0, 0);
    acc = __builtin_amdgcn_mfma_f32_16x16x32_bf16(a1, b1, acc, 0, 0, 0);
    acc = __builtin_amdgcn_mfma_f32_16x16x32_bf16(a2, b2, acc, 0, 0, 0);
    acc = __builtin_amdgcn_mfma_f32_16x16x32_bf16(a3, b3, acc, 0, 0, 0);
    // C/D: col=lane&15, row=q*4+r ; feats nt*16..+16 -> plane nt>>1, off (nt&1)*16+m
    unsigned char* op = H + (size_t)(nt >> 1) * planeStride
                          + (size_t)(row16 + q * 4) * 32 + (nt & 1) * 16 + m;
    op[0]  = (unsigned char)(__builtin_amdgcn_cvt_pk_fp8_f32(acc[0], acc[0], 0, false) & 0xFF);
    op[32] = (unsigned char)(__builtin_amdgcn_cvt_pk_fp8_f32(acc[1], acc[1], 0, false) & 0xFF);
    op[64] = (unsigned char)(__builtin_amdgcn_cvt_pk_fp8_f32(acc[2], acc[2], 0, false) & 0xFF);
    op[96] = (unsigned char)(__builtin_amdgcn_cvt_pk_fp8_f32(acc[3], acc[3], 0, false) & 0xFF);
  }
}

// ---------- k_agg: XCD-sliced, slot-parallel.
// Block's slice sl=(blockIdx&7)>>1 (2 XCDs per plane; plane 3.2MB L2-resident).
// Wave = 16 slots x 4 lanes; each slot walks one dst node's edge list serially;
// lane q covers feats sl*32 + q*8 .. +8 (uint2 fp8). No per-node shuffles. ----------
__global__ void __launch_bounds__(256) k_agg(const unsigned char* __restrict__ H,
    const int2* __restrict__ rc, const float2* __restrict__ dc,
    const unsigned* __restrict__ edges, const void* __restrict__ b1,
    float* __restrict__ v, int N, int nblk, const int* __restrict__ flagp){
  __shared__ float vsh[32];
  int tid = threadIdx.x;
  if (tid < 32) vsh[tid] = 0.0f;
  __syncthreads();
  int isf32 = *flagp;
  int lane = tid & 63;
  int wv = tid >> 6;                  // wave in block 0..3
  int slot = lane >> 2;               // 0..15
  int q = lane & 3;                   // feature quarter within slice
  int sl = (blockIdx.x & 7) >> 1;     // slice/plane 0..3
  int jblk = (int)(blockIdx.x >> 3) * 2 + (blockIdx.x & 1);   // rank within slice
  int slotg = (jblk * 4 + wv) * 16 + slot;
  int totslots = (nblk >> 3) * 2 * 4 * 16;
  const unsigned char* Hp = H + (size_t)sl * ((size_t)N * 32);
  int fbase = sl * 32 + q * 8;
  float bx[8];
  #pragma unroll
  for (int j = 0; j < 8; ++j) bx[j] = ldf(b1, fbase + j, isf32);
  float ax[8] = {0,0,0,0,0,0,0,0};
  for (int d = slotg; d < N; d += totslots){
    int2  rcv = rc[d];                 // (rowptr, cnt)
    float2 dcv = dc[d];                // (dinv^2, cfac)
    float acc[8] = {0,0,0,0,0,0,0,0};
    uint2 hs = *(const uint2*)(Hp + (size_t)d * 32 + q * 8);
    fma8f8(acc, dcv.x, hs);            // self-loop term
    int p = rcv.x, pe = rcv.x + rcv.y;
    for (; p < pe; ++p){
      unsigned r = edges[p];
      uint2 h = *(const uint2*)(Hp + (size_t)(r >> 15) * 32 + q * 8);
      fma8f8(acc, (float)(r & 32767u) * (1.0f / 32768.0f), h);
    }
    #pragma unroll
    for (int j = 0; j < 8; ++j){
      float rj = fmaxf(acc[j] + bx[j], 0.0f);
      ax[j] = fmaf(dcv.y, rj, ax[j]);
    }
  }
  // cross-slot reduce (lane bits 2..5), once per wave
  #pragma unroll
  for (int j = 0; j < 8; ++j){
    ax[j] += __shfl_xor(ax[j], 4);
    ax[j] += __shfl_xor(ax[j], 8);
    ax[j] += __shfl_xor(ax[j], 16);
    ax[j] += __shfl_xor(ax[j], 32);
  }
  if (slot == 0){
    #pragma unroll
    for (int j = 0; j < 8; ++j) atomicAdd(&vsh[q * 8 + j], ax[j]);
  }
  __syncthreads();
  if (tid < 32) atomicAdd(&v[sl * 32 + tid], vsh[tid]);
}

// ---------- tiny head ----------
__global__ void __launch_bounds__(128) k_head(const float* __restrict__ v,
    const void* __restrict__ W2, const void* __restrict__ b2,
    const void* __restrict__ Wmu, const void* __restrict__ bmu,
    const void* __restrict__ Wlv, const void* __restrict__ blv,
    void* __restrict__ outv, float invN, const int* __restrict__ flagp){
  __shared__ float gsh[128];
  __shared__ float tsh[128];
  int t = threadIdx.x;
  int isf32 = *flagp;
  gsh[t] = v[t] * invN;
  __syncthreads();
  float acc = ldf(b2, t, isf32);
  for (int k = 0; k < 128; ++k) acc = fmaf(gsh[k], ldf(W2, k * 128 + t, isf32), acc);
  tsh[t] = acc;
  __syncthreads();
  int j = t & 63;
  const void* Wp = (t < 64) ? Wmu : Wlv;
  float o = ldf((t < 64) ? bmu : blv, j, isf32);
  for (int k = 0; k < 128; ++k) o = fmaf(tsh[k], ldf(Wp, k * 64 + j, isf32), o);
  if (isf32) ((float*)outv)[t] = o;
  else       ((unsigned short*)outv)[t] = f2bf(o);
}

extern "C" void kernel_launch(void* const* d_in, const int* in_sizes, int n_in,
                              void* d_out, int out_size, void* d_ws, size_t ws_size,
                              hipStream_t stream) {
  const void* x   = d_in[0];
  const int*  ei  = (const int*)d_in[1];
  const void* w   = d_in[2];
  const void* W1  = d_in[3];
  const void* b1  = d_in[4];
  const void* W2  = d_in[5];
  const void* b2  = d_in[6];
  const void* Wmu = d_in[7];
  const void* bmu = d_in[8];
  const void* Wlv = d_in[9];
  const void* blv = d_in[10];

  const int N = in_sizes[0] / 128;     // 100000
  const int E = in_sizes[2];           // 1600000
  const int* src = ei;
  const int* dst = ei + E;

  char* wsb = (char*)d_ws;
  size_t off = 0;
  auto alloc = [&](size_t bytes) -> void* {
    off = (off + 255) & ~(size_t)255;
    void* p = wsb + off;
    off += bytes;
    return p;
  };
  int*   flag     = (int*)  alloc(16);
  float* dinv     = (float*)alloc((size_t)N * 4);
  int*   cnt      = (int*)  alloc((size_t)N * 4);
  int*   rowptr   = (int*)  alloc((size_t)(N + 1) * 4);
  u64*   sbasePk  = (u64*)  alloc((size_t)N * 8);
  float2* dc      = (float2*)alloc((size_t)N * 8);
  int2*   rc      = (int2*) alloc((size_t)N * 8);
  int*   bsum     = (int*)  alloc(512 * 4);
  int*   boffs    = (int*)  alloc(512 * 4);
  float* v        = (float*)alloc(128 * 4);
  unsigned short* W1T = (unsigned short*)alloc(128 * 128 * 2);
  float* cfac8    = (float*)alloc((size_t)N * 8 * 4);
  unsigned* edges = (unsigned*)alloc((size_t)E * 4);
  // regionA: phase-1 {dc8 (N*8*8) | rank (E*2)} overlaid by phase-2 H (N*128*1).
  size_t dc8_b  = (size_t)N * 8 * 8;
  size_t rank_b = (size_t)E * 2;
  size_t H_b    = (size_t)N * 128;
  size_t regA   = dc8_b + rank_b > H_b ? dc8_b + rank_b : H_b;
  char* regionA = (char*)alloc(regA);
  u64*            dc8  = (u64*)regionA;
  unsigned short* rank = (unsigned short*)(regionA + dc8_b);
  unsigned char*  H    = (unsigned char*)regionA;
  (void)ws_size; (void)n_in; (void)out_size;

  const int nb_n = (N + 255) / 256;    // 391
  const int nb_e = (E + 255) / 256;    // 6250

  k_detect<<<1, 256, 0, stream>>>((const unsigned*)x, flag);
  k_init<<<nb_n, 256, 0, stream>>>(dc8, cfac8, v, N);
  k_pass1<<<nb_e, 256, 0, stream>>>(dst, w, dc8, rank, E, N, flag);
  k_dinv<<<nb_n, 256, 0, stream>>>(dc8, dinv, cnt, sbasePk, N);
  k_scanA<<<nb_n, 256, 0, stream>>>(cnt, rowptr, bsum, N);
  k_scanB<<<1, 512, 0, stream>>>(bsum, boffs, nb_n);
  k_scanC<<<nb_n, 256, 0, stream>>>(rowptr, boffs, N);
  k_fill<<<nb_e, 256, 0, stream>>>(src, dst, w, dinv, rowptr, sbasePk, rank,
                                   edges, cfac8, E, N, flag);
  k_cfacm<<<nb_n, 256, 0, stream>>>(cfac8, dinv, rowptr, cnt, dc, rc, N);
  k_transpose<<<64, 256, 0, stream>>>(W1, W1T, flag);
  const int nwaves = (N + 15) / 16;
  const int nb_g = (nwaves + 3) / 4;
  k_gemm<<<nb_g, 256, 0, stream>>>(x, (const __bf16*)W1T, H, N, flag);
  const int nb_agg = 2048;             // 8 blocks/CU, one dispatch round
  k_agg<<<nb_agg, 256, 0, stream>>>(H, rc, dc, edges, b1, v, N, nb_agg, flag);
  k_head<<<1, 128, 0, stream>>>(v, W2, b2, Wmu, bmu, Wlv, blv,
                                d_out, 1.0f / (float)N, flag);
}